// Round 1
// 1255.863 us; speedup vs baseline: 1.0580x; 1.0580x over previous
//
#include <hip/hip_runtime.h>
#include <stdint.h>

#define E_EDGES 800000
#define NN 50000
#define IN_CH 128
#define HID 64        // real hidden dims (32 complex)
#define OUT_CH 128
#define KTOT 192      // HID + IN_CH
#define BM 64

typedef __attribute__((ext_vector_type(8))) short short8;
typedef __attribute__((ext_vector_type(4))) float f32x4;

__device__ __forceinline__ uint32_t f2bf1(float f) {
    union { float f; uint32_t u; } v; v.f = f;
    return (v.u + 0x7FFFu + ((v.u >> 16) & 1u)) >> 16;  // RNE to bf16
}
__device__ __forceinline__ uint32_t pack2(float a, float b) {
    return f2bf1(a) | (f2bf1(b) << 16);
}

// ---- prep: repack weights to bf16, fuse biases ----
__global__ void prep_kernel(const float* __restrict__ W_in, const float* __restrict__ W_out,
                            const float* __restrict__ W_skip, const float* __restrict__ b_skip,
                            const float* __restrict__ bias,
                            unsigned short* __restrict__ Wb1,   // [64][128] bf16
                            unsigned short* __restrict__ Bt2,   // [128][192] bf16 (B^T: [n][k])
                            float* __restrict__ cb)             // [128]
{
    int t = blockIdx.x * blockDim.x + threadIdx.x;
    int stride = gridDim.x * blockDim.x;
    for (int i = t; i < HID * IN_CH; i += stride) Wb1[i] = (unsigned short)f2bf1(W_in[i]);
    for (int i = t; i < OUT_CH * KTOT; i += stride) {
        int n = i / KTOT, k = i % KTOT;
        float v = (k < HID) ? W_out[n * HID + k] : W_skip[n * IN_CH + (k - HID)];
        Bt2[i] = (unsigned short)f2bf1(v);
    }
    if (t < OUT_CH) cb[t] = b_skip[t] + bias[t];
}

// ---- CSR build: count incidences per node ----
__global__ __launch_bounds__(256)
void count_kernel(const int* __restrict__ ei, int* __restrict__ cnt)
{
    int e = blockIdx.x * 256 + threadIdx.x;
    if (e < E_EDGES) {
        atomicAdd(&cnt[ei[E_EDGES + e]], 1);  // head node v
        atomicAdd(&cnt[ei[e]], 1);            // tail node u
    }
}

// ---- CSR build: exclusive scan (single block, 1024 threads, 49 elems/thread) ----
__global__ __launch_bounds__(1024)
void scan_kernel(const int* __restrict__ cnt, int* __restrict__ off, int* __restrict__ cur)
{
    __shared__ int part[1024];
    const int t = threadIdx.x;
    const int CH = (NN + 1023) >> 10;  // 49
    const int base = t * CH;
    int sum = 0;
    for (int i = 0; i < CH; ++i) {
        int idx = base + i;
        if (idx < NN) sum += cnt[idx];
    }
    part[t] = sum;
    __syncthreads();
    // Hillis-Steele inclusive scan over 1024 partials
    for (int d = 1; d < 1024; d <<= 1) {
        int v = (t >= d) ? part[t - d] : 0;
        __syncthreads();
        part[t] += v;
        __syncthreads();
    }
    int prefix = (t == 0) ? 0 : part[t - 1];
    for (int i = 0; i < CH; ++i) {
        int idx = base + i;
        if (idx < NN) {
            off[idx] = prefix;
            cur[idx] = prefix;
            prefix += cnt[idx];
        }
    }
    if (t == 1023) off[NN] = part[1023];
}

// ---- CSR build: fill adjacency (entry = e<<1 | role; role 0=head@v, 1=tail@u) ----
__global__ __launch_bounds__(256)
void fill_kernel(const int* __restrict__ ei, int* __restrict__ cur, int* __restrict__ adj)
{
    int e = blockIdx.x * 256 + threadIdx.x;
    if (e < E_EDGES) {
        int u = ei[e], v = ei[E_EDGES + e];
        int pv = atomicAdd(&cur[v], 1); adj[pv] = (e << 1);
        int pu = atomicAdd(&cur[u], 1); adj[pu] = (e << 1) | 1;
    }
}

// ---- k1z: Z = attr @ W_in^T (bf16 MFMA), scale by dinv, store fp32 Z (NO atomics) ----
// Zf lives in the first 204.8 MB of the output buffer; k2 fully overwrites out later.
__global__ __launch_bounds__(256)
void k1z_kernel(const float* __restrict__ attr, const int* __restrict__ ei,
                const int* __restrict__ msk, const unsigned short* __restrict__ Wb1,
                float* __restrict__ Zf)
{
    __shared__ __align__(16) unsigned short sA[BM][136];   // attr tile bf16
    __shared__ __align__(16) unsigned short sW[HID][136];  // W_in bf16
    __shared__ float sZ[BM][68];                           // fp32 Z tile

    const int t  = threadIdx.x;
    const int e0 = blockIdx.x * BM;

    // stage W_in (8192 bf16 = 1024 x 16B)
    {
        const uint4* src = (const uint4*)Wb1;
        #pragma unroll
        for (int i = 0; i < 4; ++i) {
            int idx = t + i * 256;
            uint4 val = src[idx];
            *(uint4*)&sW[idx >> 4][(idx & 15) * 8] = val;
        }
    }
    // stage attr tile, fp32 -> bf16
    {
        int r = t >> 5, seg = t & 31;
        #pragma unroll
        for (int i = 0; i < 8; ++i) {
            int row = r + i * 8;
            float4 a = *(const float4*)&attr[(e0 + row) * IN_CH + seg * 4];
            uint2 pk; pk.x = pack2(a.x, a.y); pk.y = pack2(a.z, a.w);
            *(uint2*)&sA[row][seg * 4] = pk;
        }
    }
    __syncthreads();

    const int w = t >> 6, l = t & 63, lr = l & 15, quad = l >> 4;
    f32x4 acc[4] = {};
    #pragma unroll
    for (int kk = 0; kk < 4; ++kk) {
        short8 a = *(const short8*)&sA[w * 16 + lr][kk * 32 + quad * 8];
        #pragma unroll
        for (int nt = 0; nt < 4; ++nt) {
            short8 b = *(const short8*)&sW[nt * 16 + lr][kk * 32 + quad * 8];
            acc[nt] = __builtin_amdgcn_mfma_f32_16x16x32_bf16(a, b, acc[nt], 0, 0, 0);
        }
    }
    // C layout: col = lane&15, row = quad*4 + reg
    #pragma unroll
    for (int nt = 0; nt < 4; ++nt)
        #pragma unroll
        for (int r = 0; r < 4; ++r)
            sZ[w * 16 + quad * 4 + r][nt * 16 + lr] = acc[nt][r];
    __syncthreads();

    // write z*dinv to global, fully coalesced (64 edges x 32 complex pairs)
    #pragma unroll
    for (int i = 0; i < 8; ++i) {
        int idx = t + i * 256;
        int el = idx >> 5, c = idx & 31;
        int e = e0 + el;
        int u = ei[e], v = ei[E_EDGES + e];
        int mk = msk[e];
        float dinv = (u == v && mk) ? 0.0f : 0.70710678f;
        float2 z2;
        z2.x = sZ[el][2 * c] * dinv;
        z2.y = sZ[el][2 * c + 1] * dinv;
        *(float2*)&Zf[(size_t)e * 64 + 2 * c] = z2;
    }
}

// ---- gather: per node, accumulate complex h from incident edges, relu, store ----
// one wave per node; lanes: sub = l>>5 picks incidence parity, lc = l&31 = complex channel
__global__ __launch_bounds__(256)
void gather_kernel(const int* __restrict__ off, const int* __restrict__ adj,
                   const int* __restrict__ msk, const float* __restrict__ Zf,
                   float* __restrict__ h)
{
    const int t = threadIdx.x;
    const int n = blockIdx.x * 4 + (t >> 6);
    const int l = t & 63, sub = l >> 5, lc = l & 31;
    const int je = off[n + 1];
    float ar = 0.f, ai = 0.f;
    for (int j = off[n] + sub; j < je; j += 2) {
        int entry = adj[j];
        int e = entry >> 1;
        int role = entry & 1;
        int mk = msk[e];
        // c_head = conj(phase) = (pr, -pi); c_tail = -phase = (-pr, -pi)
        float pr = mk ? 1.0f : 0.70710678f;
        float ci = mk ? 0.0f : -0.70710678f;
        float cr = role ? -pr : pr;
        float2 z = *(const float2*)&Zf[(size_t)e * 64 + 2 * lc];
        ar += cr * z.x - ci * z.y;
        ai += cr * z.y + ci * z.x;
    }
    // combine the two incidence-parity halves of the wave
    ar += __shfl_xor(ar, 32);
    ai += __shfl_xor(ai, 32);
    if (sub == 0) {
        float2 o;
        o.x = fmaxf(ar, 0.f);
        o.y = fmaxf(ai, 0.f);
        *(float2*)&h[(size_t)n * 64 + 2 * lc] = o;
    }
}

// ---- k2: gather h, build [y | attr] tile, MFMA with [W_out | W_skip]^T, + biases ----
__global__ __launch_bounds__(256)
void k2_kernel(const float* __restrict__ attr, const int* __restrict__ ei,
               const int* __restrict__ msk, const unsigned short* __restrict__ Bt2,
               const float* __restrict__ cb, const float* __restrict__ h,
               float* __restrict__ out)
{
    __shared__ __align__(16) unsigned short sA[BM][200];      // [64][192+8]
    __shared__ __align__(16) unsigned short sB[OUT_CH][200];  // [128][192+8]

    const int t  = threadIdx.x;
    const int e0 = blockIdx.x * BM;

    // stage B^T (24576 bf16 = 3072 x 16B)
    #pragma unroll
    for (int i = 0; i < 12; ++i) {
        int idx = t + i * 256;
        int n = idx / 24, c = (idx % 24) * 8;
        uint4 val = *(const uint4*)&Bt2[n * KTOT + c];
        *(uint4*)&sB[n][c] = val;
    }
    // stage attr into k = 64..191
    {
        int r = t >> 5, seg = t & 31;
        #pragma unroll
        for (int i = 0; i < 8; ++i) {
            int row = r + i * 8;
            float4 a = *(const float4*)&attr[(e0 + row) * IN_CH + seg * 4];
            uint2 pk; pk.x = pack2(a.x, a.y); pk.y = pack2(a.z, a.w);
            *(uint2*)&sA[row][HID + seg * 4] = pk;
        }
    }
    // gather + relu + complex combine -> y into k = 0..63
    {
        int el = t >> 2, part = t & 3;
        int e = e0 + el;
        int u = ei[e], v = ei[E_EDGES + e];
        int mk = msk[e];
        float pr = mk ? 1.0f : 0.70710678f;
        float pi = mk ? 0.0f : 0.70710678f;
        float dinv = (u == v && mk) ? 0.0f : 0.70710678f;
        const float4* hv = (const float4*)&h[v * HID + part * 16];
        const float4* hu = (const float4*)&h[u * HID + part * 16];
        #pragma unroll
        for (int q = 0; q < 4; ++q) {
            float4 a4 = hv[q], b4 = hu[q];
            float ar0 = fmaxf(a4.x, 0.f), ai0 = fmaxf(a4.y, 0.f);
            float ar1 = fmaxf(a4.z, 0.f), ai1 = fmaxf(a4.w, 0.f);
            float br0 = fmaxf(b4.x, 0.f), bi0 = fmaxf(b4.y, 0.f);
            float br1 = fmaxf(b4.z, 0.f), bi1 = fmaxf(b4.w, 0.f);
            // y = dinv * ( p * relu(h[v]) - conj(p) * relu(h[u]) )
            float yr0 = dinv * ((pr * ar0 - pi * ai0) - (pr * br0 + pi * bi0));
            float yi0 = dinv * ((pr * ai0 + pi * ar0) - (pr * bi0 - pi * br0));
            float yr1 = dinv * ((pr * ar1 - pi * ai1) - (pr * br1 + pi * bi1));
            float yi1 = dinv * ((pr * ai1 + pi * ar1) - (pr * bi1 - pi * br1));
            uint2 pk; pk.x = pack2(yr0, yi0); pk.y = pack2(yr1, yi1);
            *(uint2*)&sA[el][part * 16 + q * 4] = pk;
        }
    }
    __syncthreads();

    const int w = t >> 6, l = t & 63, lr = l & 15, quad = l >> 4;
    f32x4 acc[8] = {};
    #pragma unroll
    for (int kk = 0; kk < 6; ++kk) {
        short8 a = *(const short8*)&sA[w * 16 + lr][kk * 32 + quad * 8];
        #pragma unroll
        for (int nt = 0; nt < 8; ++nt) {
            short8 b = *(const short8*)&sB[nt * 16 + lr][kk * 32 + quad * 8];
            acc[nt] = __builtin_amdgcn_mfma_f32_16x16x32_bf16(a, b, acc[nt], 0, 0, 0);
        }
    }
    #pragma unroll
    for (int nt = 0; nt < 8; ++nt) {
        int col = nt * 16 + lr;
        float cbv = cb[col];
        #pragma unroll
        for (int r = 0; r < 4; ++r) {
            int row = w * 16 + quad * 4 + r;
            out[(e0 + row) * OUT_CH + col] = acc[nt][r] + cbv;
        }
    }
}

extern "C" void kernel_launch(void* const* d_in, const int* in_sizes, int n_in,
                              void* d_out, int out_size, void* d_ws, size_t ws_size,
                              hipStream_t stream)
{
    const int*   ei    = (const int*)d_in[0];    // [2][E]
    const int*   msk   = (const int*)d_in[1];    // [E] bool as int
    const float* attr  = (const float*)d_in[2];  // [E][128]
    const float* W_in  = (const float*)d_in[3];  // [64][128]
    const float* W_out = (const float*)d_in[4];  // [128][64]
    const float* W_skp = (const float*)d_in[5];  // [128][128]
    const float* b_skp = (const float*)d_in[6];  // [128]
    const float* bias  = (const float*)d_in[7];  // [128]
    float* out = (float*)d_out;
    float* Zf  = (float*)d_out;   // scratch: first E*64*4 = 204.8 MB of out; k2 overwrites all of out

    char* ws = (char*)d_ws;
    float*          h   = (float*)ws;                          // 12,800,000 B
    unsigned short* Wb1 = (unsigned short*)(ws + 12800000);    // 16,384 B
    unsigned short* Bt2 = (unsigned short*)(ws + 12816384);    // 49,152 B
    float*          cb  = (float*)(ws + 12865536);             // 512 B
    int*            cnt = (int*)(ws + 12866048);               // 200,000 B
    int*            off = (int*)(ws + 13066112);               // 200,004 B (padded)
    int*            cur = (int*)(ws + 13266176);               // 200,000 B
    int*            adj = (int*)(ws + 13466240);               // 6,400,000 B  (end ~19.87 MB)

    hipMemsetAsync(cnt, 0, NN * sizeof(int), stream);
    prep_kernel<<<64, 256, 0, stream>>>(W_in, W_out, W_skp, b_skp, bias, Wb1, Bt2, cb);
    count_kernel<<<(E_EDGES + 255) / 256, 256, 0, stream>>>(ei, cnt);
    scan_kernel<<<1, 1024, 0, stream>>>(cnt, off, cur);
    fill_kernel<<<(E_EDGES + 255) / 256, 256, 0, stream>>>(ei, cur, adj);
    k1z_kernel<<<E_EDGES / BM, 256, 0, stream>>>(attr, ei, msk, Wb1, Zf);
    gather_kernel<<<NN / 4, 256, 0, stream>>>(off, adj, msk, Zf, h);
    k2_kernel<<<E_EDGES / BM, 256, 0, stream>>>(attr, ei, msk, Bt2, cb, h, out);
}

// Round 2
// 1163.870 us; speedup vs baseline: 1.1417x; 1.0790x over previous
//
#include <hip/hip_runtime.h>
#include <stdint.h>

#define E_EDGES 800000
#define NN 50000
#define IN_CH 128
#define HID 64        // real hidden dims (32 complex)
#define OUT_CH 128
#define KTOT 192      // HID + IN_CH
#define BM 64

typedef __attribute__((ext_vector_type(8))) short short8;
typedef __attribute__((ext_vector_type(4))) float f32x4;

__device__ __forceinline__ uint32_t f2bf1(float f) {
    union { float f; uint32_t u; } v; v.f = f;
    return (v.u + 0x7FFFu + ((v.u >> 16) & 1u)) >> 16;  // RNE to bf16
}
__device__ __forceinline__ uint32_t pack2(float a, float b) {
    return f2bf1(a) | (f2bf1(b) << 16);
}
__device__ __forceinline__ float bflo(uint32_t u) {
    union { uint32_t u; float f; } v; v.u = u << 16; return v.f;
}
__device__ __forceinline__ float bfhi(uint32_t u) {
    union { uint32_t u; float f; } v; v.u = u & 0xFFFF0000u; return v.f;
}

// ---- prep: repack weights to bf16, fuse biases, zero cnt ----
__global__ void prep_kernel(const float* __restrict__ W_in, const float* __restrict__ W_out,
                            const float* __restrict__ W_skip, const float* __restrict__ b_skip,
                            const float* __restrict__ bias,
                            unsigned short* __restrict__ Wb1,   // [64][128] bf16
                            unsigned short* __restrict__ Bt2,   // [128][192] bf16 (B^T: [n][k])
                            float* __restrict__ cb,             // [128]
                            int* __restrict__ cnt)              // [NN] zeroed here
{
    int t = blockIdx.x * blockDim.x + threadIdx.x;
    int stride = gridDim.x * blockDim.x;
    for (int i = t; i < NN; i += stride) cnt[i] = 0;
    for (int i = t; i < HID * IN_CH; i += stride) Wb1[i] = (unsigned short)f2bf1(W_in[i]);
    for (int i = t; i < OUT_CH * KTOT; i += stride) {
        int n = i / KTOT, k = i % KTOT;
        float v = (k < HID) ? W_out[n * HID + k] : W_skip[n * IN_CH + (k - HID)];
        Bt2[i] = (unsigned short)f2bf1(v);
    }
    if (t < OUT_CH) cb[t] = b_skip[t] + bias[t];
}

// ---- CSR build: exclusive scan (single block, 1024 threads, 49 elems/thread) ----
__global__ __launch_bounds__(1024)
void scan_kernel(const int* __restrict__ cnt, int* __restrict__ off, int* __restrict__ cur)
{
    __shared__ int part[1024];
    const int t = threadIdx.x;
    const int CH = (NN + 1023) >> 10;  // 49
    const int base = t * CH;
    int sum = 0;
    for (int i = 0; i < CH; ++i) {
        int idx = base + i;
        if (idx < NN) sum += cnt[idx];
    }
    part[t] = sum;
    __syncthreads();
    // Hillis-Steele inclusive scan over 1024 partials
    for (int d = 1; d < 1024; d <<= 1) {
        int v = (t >= d) ? part[t - d] : 0;
        __syncthreads();
        part[t] += v;
        __syncthreads();
    }
    int prefix = (t == 0) ? 0 : part[t - 1];
    for (int i = 0; i < CH; ++i) {
        int idx = base + i;
        if (idx < NN) {
            off[idx] = prefix;
            cur[idx] = prefix;
            prefix += cnt[idx];
        }
    }
    if (t == 1023) off[NN] = part[1023];
}

// ---- CSR build: fill adjacency (entry = e<<1 | role; role 0=head@v, 1=tail@u) ----
__global__ __launch_bounds__(256)
void fill_kernel(const int* __restrict__ ei, int* __restrict__ cur, int* __restrict__ adj)
{
    int e = blockIdx.x * 256 + threadIdx.x;
    if (e < E_EDGES) {
        int u = ei[e], v = ei[E_EDGES + e];
        int pv = atomicAdd(&cur[v], 1); adj[pv] = (e << 1);
        int pu = atomicAdd(&cur[u], 1); adj[pu] = (e << 1) | 1;
    }
}

// ---- k1zc: Z = attr @ W_in^T (bf16 MFMA), scale by dinv, store bf16-packed Z.
//      Also counts node incidences (fused count_kernel), hidden under the MFMA. ----
__global__ __launch_bounds__(256)
void k1zc_kernel(const float* __restrict__ attr, const int* __restrict__ ei,
                 const int* __restrict__ msk, const unsigned short* __restrict__ Wb1,
                 uint32_t* __restrict__ Zf, int* __restrict__ cnt)
{
    __shared__ __align__(16) unsigned short sA[BM][136];   // attr tile bf16
    __shared__ __align__(16) unsigned short sW[HID][136];  // W_in bf16
    __shared__ float sZ[BM][68];                           // fp32 Z tile

    const int t  = threadIdx.x;
    const int e0 = blockIdx.x * BM;

    // fused incidence count: one edge per thread (threads 0..63), drains under GEMM
    if (t < BM) {
        int e = e0 + t;
        atomicAdd(&cnt[ei[E_EDGES + e]], 1);  // head v
        atomicAdd(&cnt[ei[e]], 1);            // tail u
    }

    // stage W_in (8192 bf16 = 1024 x 16B)
    {
        const uint4* src = (const uint4*)Wb1;
        #pragma unroll
        for (int i = 0; i < 4; ++i) {
            int idx = t + i * 256;
            uint4 val = src[idx];
            *(uint4*)&sW[idx >> 4][(idx & 15) * 8] = val;
        }
    }
    // stage attr tile, fp32 -> bf16
    {
        int r = t >> 5, seg = t & 31;
        #pragma unroll
        for (int i = 0; i < 8; ++i) {
            int row = r + i * 8;
            float4 a = *(const float4*)&attr[(e0 + row) * IN_CH + seg * 4];
            uint2 pk; pk.x = pack2(a.x, a.y); pk.y = pack2(a.z, a.w);
            *(uint2*)&sA[row][seg * 4] = pk;
        }
    }
    __syncthreads();

    const int w = t >> 6, l = t & 63, lr = l & 15, quad = l >> 4;
    f32x4 acc[4] = {};
    #pragma unroll
    for (int kk = 0; kk < 4; ++kk) {
        short8 a = *(const short8*)&sA[w * 16 + lr][kk * 32 + quad * 8];
        #pragma unroll
        for (int nt = 0; nt < 4; ++nt) {
            short8 b = *(const short8*)&sW[nt * 16 + lr][kk * 32 + quad * 8];
            acc[nt] = __builtin_amdgcn_mfma_f32_16x16x32_bf16(a, b, acc[nt], 0, 0, 0);
        }
    }
    // C layout: col = lane&15, row = quad*4 + reg
    #pragma unroll
    for (int nt = 0; nt < 4; ++nt)
        #pragma unroll
        for (int r = 0; r < 4; ++r)
            sZ[w * 16 + quad * 4 + r][nt * 16 + lr] = acc[nt][r];
    __syncthreads();

    // write z*dinv to global as packed bf16 pairs, fully coalesced
    #pragma unroll
    for (int i = 0; i < 8; ++i) {
        int idx = t + i * 256;
        int el = idx >> 5, c = idx & 31;
        int e = e0 + el;
        int u = ei[e], v = ei[E_EDGES + e];
        int mk = msk[e];
        float dinv = (u == v && mk) ? 0.0f : 0.70710678f;
        float zr = sZ[el][2 * c] * dinv;
        float zi = sZ[el][2 * c + 1] * dinv;
        Zf[(size_t)e * 32 + c] = pack2(zr, zi);
    }
}

// ---- gather: per node, accumulate complex h from incident edges, relu, store ----
// one wave per node; lanes: sub = l>>5 picks incidence parity, lc = l&31 = complex channel
__global__ __launch_bounds__(256)
void gather_kernel(const int* __restrict__ off, const int* __restrict__ adj,
                   const int* __restrict__ msk, const uint32_t* __restrict__ Zf,
                   float* __restrict__ h)
{
    const int t = threadIdx.x;
    const int n = blockIdx.x * 4 + (t >> 6);
    const int l = t & 63, sub = l >> 5, lc = l & 31;
    const int je = off[n + 1];
    float ar = 0.f, ai = 0.f;
    for (int j = off[n] + sub; j < je; j += 2) {
        int entry = adj[j];
        int e = entry >> 1;
        int role = entry & 1;
        int mk = msk[e];
        // c_head = conj(phase) = (pr, -pi); c_tail = -phase = (-pr, -pi)
        float pr = mk ? 1.0f : 0.70710678f;
        float ci = mk ? 0.0f : -0.70710678f;
        float cr = role ? -pr : pr;
        uint32_t zp = Zf[(size_t)e * 32 + lc];
        float zx = bflo(zp), zy = bfhi(zp);
        ar += cr * zx - ci * zy;
        ai += cr * zy + ci * zx;
    }
    // combine the two incidence-parity halves of the wave
    ar += __shfl_xor(ar, 32);
    ai += __shfl_xor(ai, 32);
    if (sub == 0) {
        float2 o;
        o.x = fmaxf(ar, 0.f);
        o.y = fmaxf(ai, 0.f);
        *(float2*)&h[(size_t)n * 64 + 2 * lc] = o;
    }
}

// ---- k2: gather h, build [y | attr] tile, MFMA with [W_out | W_skip]^T, + biases ----
__global__ __launch_bounds__(256)
void k2_kernel(const float* __restrict__ attr, const int* __restrict__ ei,
               const int* __restrict__ msk, const unsigned short* __restrict__ Bt2,
               const float* __restrict__ cb, const float* __restrict__ h,
               float* __restrict__ out)
{
    __shared__ __align__(16) unsigned short sA[BM][200];      // [64][192+8]
    __shared__ __align__(16) unsigned short sB[OUT_CH][200];  // [128][192+8]

    const int t  = threadIdx.x;
    const int e0 = blockIdx.x * BM;

    // stage B^T (24576 bf16 = 3072 x 16B)
    #pragma unroll
    for (int i = 0; i < 12; ++i) {
        int idx = t + i * 256;
        int n = idx / 24, c = (idx % 24) * 8;
        uint4 val = *(const uint4*)&Bt2[n * KTOT + c];
        *(uint4*)&sB[n][c] = val;
    }
    // stage attr into k = 64..191
    {
        int r = t >> 5, seg = t & 31;
        #pragma unroll
        for (int i = 0; i < 8; ++i) {
            int row = r + i * 8;
            float4 a = *(const float4*)&attr[(e0 + row) * IN_CH + seg * 4];
            uint2 pk; pk.x = pack2(a.x, a.y); pk.y = pack2(a.z, a.w);
            *(uint2*)&sA[row][HID + seg * 4] = pk;
        }
    }
    // gather + relu + complex combine -> y into k = 0..63
    {
        int el = t >> 2, part = t & 3;
        int e = e0 + el;
        int u = ei[e], v = ei[E_EDGES + e];
        int mk = msk[e];
        float pr = mk ? 1.0f : 0.70710678f;
        float pi = mk ? 0.0f : 0.70710678f;
        float dinv = (u == v && mk) ? 0.0f : 0.70710678f;
        const float4* hv = (const float4*)&h[v * HID + part * 16];
        const float4* hu = (const float4*)&h[u * HID + part * 16];
        #pragma unroll
        for (int q = 0; q < 4; ++q) {
            float4 a4 = hv[q], b4 = hu[q];
            float ar0 = fmaxf(a4.x, 0.f), ai0 = fmaxf(a4.y, 0.f);
            float ar1 = fmaxf(a4.z, 0.f), ai1 = fmaxf(a4.w, 0.f);
            float br0 = fmaxf(b4.x, 0.f), bi0 = fmaxf(b4.y, 0.f);
            float br1 = fmaxf(b4.z, 0.f), bi1 = fmaxf(b4.w, 0.f);
            // y = dinv * ( p * relu(h[v]) - conj(p) * relu(h[u]) )
            float yr0 = dinv * ((pr * ar0 - pi * ai0) - (pr * br0 + pi * bi0));
            float yi0 = dinv * ((pr * ai0 + pi * ar0) - (pr * bi0 - pi * br0));
            float yr1 = dinv * ((pr * ar1 - pi * ai1) - (pr * br1 + pi * bi1));
            float yi1 = dinv * ((pr * ai1 + pi * ar1) - (pr * bi1 - pi * br1));
            uint2 pk; pk.x = pack2(yr0, yi0); pk.y = pack2(yr1, yi1);
            *(uint2*)&sA[el][part * 16 + q * 4] = pk;
        }
    }
    __syncthreads();

    const int w = t >> 6, l = t & 63, lr = l & 15, quad = l >> 4;
    f32x4 acc[8] = {};
    #pragma unroll
    for (int kk = 0; kk < 6; ++kk) {
        short8 a = *(const short8*)&sA[w * 16 + lr][kk * 32 + quad * 8];
        #pragma unroll
        for (int nt = 0; nt < 8; ++nt) {
            short8 b = *(const short8*)&sB[nt * 16 + lr][kk * 32 + quad * 8];
            acc[nt] = __builtin_amdgcn_mfma_f32_16x16x32_bf16(a, b, acc[nt], 0, 0, 0);
        }
    }
    #pragma unroll
    for (int nt = 0; nt < 8; ++nt) {
        int col = nt * 16 + lr;
        float cbv = cb[col];
        #pragma unroll
        for (int r = 0; r < 4; ++r) {
            int row = w * 16 + quad * 4 + r;
            out[(e0 + row) * OUT_CH + col] = acc[nt][r] + cbv;
        }
    }
}

extern "C" void kernel_launch(void* const* d_in, const int* in_sizes, int n_in,
                              void* d_out, int out_size, void* d_ws, size_t ws_size,
                              hipStream_t stream)
{
    const int*   ei    = (const int*)d_in[0];    // [2][E]
    const int*   msk   = (const int*)d_in[1];    // [E] bool as int
    const float* attr  = (const float*)d_in[2];  // [E][128]
    const float* W_in  = (const float*)d_in[3];  // [64][128]
    const float* W_out = (const float*)d_in[4];  // [128][64]
    const float* W_skp = (const float*)d_in[5];  // [128][128]
    const float* b_skp = (const float*)d_in[6];  // [128]
    const float* bias  = (const float*)d_in[7];  // [128]
    float* out = (float*)d_out;
    uint32_t* Zf = (uint32_t*)d_out;  // scratch: first E*32*4 = 102.4 MB of out; k2 overwrites all of out

    char* ws = (char*)d_ws;
    float*          h   = (float*)ws;                          // 12,800,000 B
    unsigned short* Wb1 = (unsigned short*)(ws + 12800000);    // 16,384 B
    unsigned short* Bt2 = (unsigned short*)(ws + 12816384);    // 49,152 B
    float*          cb  = (float*)(ws + 12865536);             // 512 B
    int*            cnt = (int*)(ws + 12866048);               // 200,000 B
    int*            off = (int*)(ws + 13066112);               // 200,004 B (padded)
    int*            cur = (int*)(ws + 13266176);               // 200,000 B
    int*            adj = (int*)(ws + 13466240);               // 6,400,000 B  (end ~19.87 MB)

    prep_kernel<<<64, 256, 0, stream>>>(W_in, W_out, W_skp, b_skp, bias, Wb1, Bt2, cb, cnt);
    k1zc_kernel<<<E_EDGES / BM, 256, 0, stream>>>(attr, ei, msk, Wb1, Zf, cnt);
    scan_kernel<<<1, 1024, 0, stream>>>(cnt, off, cur);
    fill_kernel<<<(E_EDGES + 255) / 256, 256, 0, stream>>>(ei, cur, adj);
    gather_kernel<<<NN / 4, 256, 0, stream>>>(off, adj, msk, Zf, h);
    k2_kernel<<<E_EDGES / BM, 256, 0, stream>>>(attr, ei, msk, Bt2, cb, h, out);
}

// Round 3
// 1085.212 us; speedup vs baseline: 1.2244x; 1.0725x over previous
//
#include <hip/hip_runtime.h>
#include <stdint.h>

#define E_EDGES 800000
#define NN 50000
#define IN_CH 128
#define HID 64        // real hidden dims (32 complex)
#define OUT_CH 128
#define KTOT 192      // HID + IN_CH
#define BM 64

typedef __attribute__((ext_vector_type(8))) short short8;
typedef __attribute__((ext_vector_type(4))) float f32x4;

__device__ __forceinline__ uint32_t f2bf1(float f) {
    union { float f; uint32_t u; } v; v.f = f;
    return (v.u + 0x7FFFu + ((v.u >> 16) & 1u)) >> 16;  // RNE to bf16
}
__device__ __forceinline__ uint32_t pack2(float a, float b) {
    return f2bf1(a) | (f2bf1(b) << 16);
}
__device__ __forceinline__ float bflo(uint32_t u) {
    union { uint32_t u; float f; } v; v.u = u << 16; return v.f;
}
__device__ __forceinline__ float bfhi(uint32_t u) {
    union { uint32_t u; float f; } v; v.u = u & 0xFFFF0000u; return v.f;
}

// ---- prep: repack weights to bf16, fuse biases, zero cnt ----
__global__ void prep_kernel(const float* __restrict__ W_in, const float* __restrict__ W_out,
                            const float* __restrict__ W_skip, const float* __restrict__ b_skip,
                            const float* __restrict__ bias,
                            unsigned short* __restrict__ Wb1,   // [64][128] bf16
                            unsigned short* __restrict__ Bt2,   // [128][192] bf16 (B^T: [n][k])
                            float* __restrict__ cb,             // [128]
                            int* __restrict__ cnt)              // [NN] zeroed here
{
    int t = blockIdx.x * blockDim.x + threadIdx.x;
    int stride = gridDim.x * blockDim.x;
    for (int i = t; i < NN; i += stride) cnt[i] = 0;
    for (int i = t; i < HID * IN_CH; i += stride) Wb1[i] = (unsigned short)f2bf1(W_in[i]);
    for (int i = t; i < OUT_CH * KTOT; i += stride) {
        int n = i / KTOT, k = i % KTOT;
        float v = (k < HID) ? W_out[n * HID + k] : W_skip[n * IN_CH + (k - HID)];
        Bt2[i] = (unsigned short)f2bf1(v);
    }
    if (t < OUT_CH) cb[t] = b_skip[t] + bias[t];
}

// ---- CSR build: exclusive scan (single block, 1024 threads, 49 elems/thread) ----
__global__ __launch_bounds__(1024)
void scan_kernel(const int* __restrict__ cnt, int* __restrict__ off, int* __restrict__ cur)
{
    __shared__ int part[1024];
    const int t = threadIdx.x;
    const int CH = (NN + 1023) >> 10;  // 49
    const int base = t * CH;
    int sum = 0;
    for (int i = 0; i < CH; ++i) {
        int idx = base + i;
        if (idx < NN) sum += cnt[idx];
    }
    part[t] = sum;
    __syncthreads();
    // Hillis-Steele inclusive scan over 1024 partials
    for (int d = 1; d < 1024; d <<= 1) {
        int v = (t >= d) ? part[t - d] : 0;
        __syncthreads();
        part[t] += v;
        __syncthreads();
    }
    int prefix = (t == 0) ? 0 : part[t - 1];
    for (int i = 0; i < CH; ++i) {
        int idx = base + i;
        if (idx < NN) {
            off[idx] = prefix;
            cur[idx] = prefix;
            prefix += cnt[idx];
        }
    }
    if (t == 1023) off[NN] = part[1023];
}

// ---- CSR build: fill adjacency. entry = e<<2 | role<<1 | mask  (role 0=head@v, 1=tail@u) ----
__global__ __launch_bounds__(256)
void fill_kernel(const int* __restrict__ ei, const int* __restrict__ msk,
                 int* __restrict__ cur, int* __restrict__ adj)
{
    int e = blockIdx.x * 256 + threadIdx.x;
    if (e < E_EDGES) {
        int u = ei[e], v = ei[E_EDGES + e];
        int mk = msk[e] & 1;
        int pv = atomicAdd(&cur[v], 1); adj[pv] = (e << 2) | mk;
        int pu = atomicAdd(&cur[u], 1); adj[pu] = (e << 2) | 2 | mk;
    }
}

// ---- k1zc: Z = attr @ W_in^T (bf16 MFMA), scale by dinv, store bf16-packed Z.
//      Also counts node incidences (fused), drained under the MFMA. ----
__global__ __launch_bounds__(256)
void k1zc_kernel(const float* __restrict__ attr, const int* __restrict__ ei,
                 const int* __restrict__ msk, const unsigned short* __restrict__ Wb1,
                 uint32_t* __restrict__ Zf, int* __restrict__ cnt)
{
    __shared__ __align__(16) unsigned short sA[BM][136];   // attr tile bf16
    __shared__ __align__(16) unsigned short sW[HID][136];  // W_in bf16
    __shared__ float sZ[BM][68];                           // fp32 Z tile
    __shared__ float sDinv[BM];

    const int t  = threadIdx.x;
    const int e0 = blockIdx.x * BM;

    // per-edge metadata once: count atomics + dinv
    if (t < BM) {
        int e = e0 + t;
        int u = ei[e], v = ei[E_EDGES + e];
        int mk = msk[e];
        atomicAdd(&cnt[v], 1);
        atomicAdd(&cnt[u], 1);
        sDinv[t] = (u == v && mk) ? 0.0f : 0.70710678f;
    }

    // stage W_in (8192 bf16 = 1024 x 16B)
    {
        const uint4* src = (const uint4*)Wb1;
        #pragma unroll
        for (int i = 0; i < 4; ++i) {
            int idx = t + i * 256;
            uint4 val = src[idx];
            *(uint4*)&sW[idx >> 4][(idx & 15) * 8] = val;
        }
    }
    // stage attr tile, fp32 -> bf16
    {
        int r = t >> 5, seg = t & 31;
        #pragma unroll
        for (int i = 0; i < 8; ++i) {
            int row = r + i * 8;
            float4 a = *(const float4*)&attr[(e0 + row) * IN_CH + seg * 4];
            uint2 pk; pk.x = pack2(a.x, a.y); pk.y = pack2(a.z, a.w);
            *(uint2*)&sA[row][seg * 4] = pk;
        }
    }
    __syncthreads();

    const int w = t >> 6, l = t & 63, lr = l & 15, quad = l >> 4;
    f32x4 acc[4] = {};
    #pragma unroll
    for (int kk = 0; kk < 4; ++kk) {
        short8 a = *(const short8*)&sA[w * 16 + lr][kk * 32 + quad * 8];
        #pragma unroll
        for (int nt = 0; nt < 4; ++nt) {
            short8 b = *(const short8*)&sW[nt * 16 + lr][kk * 32 + quad * 8];
            acc[nt] = __builtin_amdgcn_mfma_f32_16x16x32_bf16(a, b, acc[nt], 0, 0, 0);
        }
    }
    // C layout: col = lane&15, row = quad*4 + reg
    #pragma unroll
    for (int nt = 0; nt < 4; ++nt)
        #pragma unroll
        for (int r = 0; r < 4; ++r)
            sZ[w * 16 + quad * 4 + r][nt * 16 + lr] = acc[nt][r];
    __syncthreads();

    // write z*dinv to global as packed bf16 pairs, fully coalesced
    #pragma unroll
    for (int i = 0; i < 8; ++i) {
        int idx = t + i * 256;
        int el = idx >> 5, c = idx & 31;
        int e = e0 + el;
        float dinv = sDinv[el];
        float zr = sZ[el][2 * c] * dinv;
        float zi = sZ[el][2 * c + 1] * dinv;
        Zf[(size_t)e * 32 + c] = pack2(zr, zi);
    }
}

// ---- gather: per node, accumulate complex h from incident edges, relu, store bf16 ----
// one wave per node; each 32-lane half takes a CONTIGUOUS half of the adjacency range,
// processes 4 incidences/iter with all 4 Zf loads in flight (latency-chain cut).
__global__ __launch_bounds__(256)
void gather_kernel(const int* __restrict__ off, const int* __restrict__ adj,
                   const uint32_t* __restrict__ Zf, uint32_t* __restrict__ hb)
{
    const int t = threadIdx.x;
    const int n = blockIdx.x * 4 + (t >> 6);
    const int l = t & 63, sub = l >> 5, lc = l & 31;
    const int jb = off[n], je = off[n + 1];
    const int half = (je - jb) >> 1;
    int j    = sub ? (jb + half) : jb;
    int jend = sub ? je : (jb + half);
    float ar = 0.f, ai = 0.f;

#define ACCZ(ENT, ZP) {                                        \
        int mk_ = (ENT) & 1;                                   \
        float pr_ = mk_ ? 1.0f : 0.70710678f;                  \
        float ci_ = mk_ ? 0.0f : -0.70710678f;                 \
        float cr_ = ((ENT) & 2) ? -pr_ : pr_;                  \
        float zx_ = bflo(ZP), zy_ = bfhi(ZP);                  \
        ar += cr_ * zx_ - ci_ * zy_;                           \
        ai += cr_ * zy_ + ci_ * zx_; }

    for (; j + 4 <= jend; j += 4) {
        int a0 = adj[j], a1 = adj[j + 1], a2 = adj[j + 2], a3 = adj[j + 3];
        uint32_t z0 = Zf[(size_t)(a0 >> 2) * 32 + lc];
        uint32_t z1 = Zf[(size_t)(a1 >> 2) * 32 + lc];
        uint32_t z2 = Zf[(size_t)(a2 >> 2) * 32 + lc];
        uint32_t z3 = Zf[(size_t)(a3 >> 2) * 32 + lc];
        ACCZ(a0, z0); ACCZ(a1, z1); ACCZ(a2, z2); ACCZ(a3, z3);
    }
    for (; j < jend; ++j) {
        int a = adj[j];
        uint32_t z = Zf[(size_t)(a >> 2) * 32 + lc];
        ACCZ(a, z);
    }
#undef ACCZ

    // combine the two contiguous halves of the wave
    ar += __shfl_xor(ar, 32);
    ai += __shfl_xor(ai, 32);
    if (sub == 0)
        hb[(size_t)n * 32 + lc] = pack2(fmaxf(ar, 0.f), fmaxf(ai, 0.f));  // post-ReLU bf16
}

// ---- k2: gather bf16 h, build [y | attr] tile, MFMA with [W_out | W_skip]^T, + biases ----
__global__ __launch_bounds__(256)
void k2_kernel(const float* __restrict__ attr, const int* __restrict__ ei,
               const int* __restrict__ msk, const unsigned short* __restrict__ Bt2,
               const float* __restrict__ cb, const uint32_t* __restrict__ hb,
               float* __restrict__ out)
{
    __shared__ __align__(16) unsigned short sA[BM][200];      // [64][192+8]
    __shared__ __align__(16) unsigned short sB[OUT_CH][200];  // [128][192+8]

    const int t  = threadIdx.x;
    const int e0 = blockIdx.x * BM;

    // stage B^T (24576 bf16 = 3072 x 16B)
    #pragma unroll
    for (int i = 0; i < 12; ++i) {
        int idx = t + i * 256;
        int n = idx / 24, c = (idx % 24) * 8;
        uint4 val = *(const uint4*)&Bt2[n * KTOT + c];
        *(uint4*)&sB[n][c] = val;
    }
    // stage attr into k = 64..191
    {
        int r = t >> 5, seg = t & 31;
        #pragma unroll
        for (int i = 0; i < 8; ++i) {
            int row = r + i * 8;
            float4 a = *(const float4*)&attr[(e0 + row) * IN_CH + seg * 4];
            uint2 pk; pk.x = pack2(a.x, a.y); pk.y = pack2(a.z, a.w);
            *(uint2*)&sA[row][HID + seg * 4] = pk;
        }
    }
    // gather bf16 h (already ReLU'd) + complex combine -> y into k = 0..63
    {
        int el = t >> 2, part = t & 3;
        int e = e0 + el;
        int u = ei[e], v = ei[E_EDGES + e];
        int mk = msk[e];
        float pr = mk ? 1.0f : 0.70710678f;
        float pi = mk ? 0.0f : 0.70710678f;
        float dinv = (u == v && mk) ? 0.0f : 0.70710678f;
        uint32_t hv[8], hu[8];
        *(uint4*)&hv[0] = *(const uint4*)&hb[(size_t)v * 32 + part * 8];
        *(uint4*)&hv[4] = *(const uint4*)&hb[(size_t)v * 32 + part * 8 + 4];
        *(uint4*)&hu[0] = *(const uint4*)&hb[(size_t)u * 32 + part * 8];
        *(uint4*)&hu[4] = *(const uint4*)&hb[(size_t)u * 32 + part * 8 + 4];
        #pragma unroll
        for (int q = 0; q < 4; ++q) {
            float ar0 = bflo(hv[2 * q]),     ai0 = bfhi(hv[2 * q]);
            float ar1 = bflo(hv[2 * q + 1]), ai1 = bfhi(hv[2 * q + 1]);
            float br0 = bflo(hu[2 * q]),     bi0 = bfhi(hu[2 * q]);
            float br1 = bflo(hu[2 * q + 1]), bi1 = bfhi(hu[2 * q + 1]);
            // y = dinv * ( p * h[v] - conj(p) * h[u] )
            float yr0 = dinv * ((pr * ar0 - pi * ai0) - (pr * br0 + pi * bi0));
            float yi0 = dinv * ((pr * ai0 + pi * ar0) - (pr * bi0 - pi * br0));
            float yr1 = dinv * ((pr * ar1 - pi * ai1) - (pr * br1 + pi * bi1));
            float yi1 = dinv * ((pr * ai1 + pi * ar1) - (pr * bi1 - pi * br1));
            uint2 pk; pk.x = pack2(yr0, yi0); pk.y = pack2(yr1, yi1);
            *(uint2*)&sA[el][part * 16 + q * 4] = pk;
        }
    }
    __syncthreads();

    const int w = t >> 6, l = t & 63, lr = l & 15, quad = l >> 4;
    f32x4 acc[8] = {};
    #pragma unroll
    for (int kk = 0; kk < 6; ++kk) {
        short8 a = *(const short8*)&sA[w * 16 + lr][kk * 32 + quad * 8];
        #pragma unroll
        for (int nt = 0; nt < 8; ++nt) {
            short8 b = *(const short8*)&sB[nt * 16 + lr][kk * 32 + quad * 8];
            acc[nt] = __builtin_amdgcn_mfma_f32_16x16x32_bf16(a, b, acc[nt], 0, 0, 0);
        }
    }
    #pragma unroll
    for (int nt = 0; nt < 8; ++nt) {
        int col = nt * 16 + lr;
        float cbv = cb[col];
        #pragma unroll
        for (int r = 0; r < 4; ++r) {
            int row = w * 16 + quad * 4 + r;
            out[(e0 + row) * OUT_CH + col] = acc[nt][r] + cbv;
        }
    }
}

extern "C" void kernel_launch(void* const* d_in, const int* in_sizes, int n_in,
                              void* d_out, int out_size, void* d_ws, size_t ws_size,
                              hipStream_t stream)
{
    const int*   ei    = (const int*)d_in[0];    // [2][E]
    const int*   msk   = (const int*)d_in[1];    // [E] bool as int
    const float* attr  = (const float*)d_in[2];  // [E][128]
    const float* W_in  = (const float*)d_in[3];  // [64][128]
    const float* W_out = (const float*)d_in[4];  // [128][64]
    const float* W_skp = (const float*)d_in[5];  // [128][128]
    const float* b_skp = (const float*)d_in[6];  // [128]
    const float* bias  = (const float*)d_in[7];  // [128]
    float* out = (float*)d_out;
    uint32_t* Zf = (uint32_t*)d_out;  // scratch: first E*32*4 = 102.4 MB of out; k2 overwrites all of out

    char* ws = (char*)d_ws;
    uint32_t*       hb  = (uint32_t*)ws;                       // 6,400,000 B (bf16-packed h)
    unsigned short* Wb1 = (unsigned short*)(ws + 12800000);    // 16,384 B
    unsigned short* Bt2 = (unsigned short*)(ws + 12816384);    // 49,152 B
    float*          cb  = (float*)(ws + 12865536);             // 512 B
    int*            cnt = (int*)(ws + 12866048);               // 200,000 B
    int*            off = (int*)(ws + 13066112);               // 200,004 B (padded)
    int*            cur = (int*)(ws + 13266176);               // 200,000 B
    int*            adj = (int*)(ws + 13466240);               // 6,400,000 B  (end ~19.87 MB)

    prep_kernel<<<64, 256, 0, stream>>>(W_in, W_out, W_skp, b_skp, bias, Wb1, Bt2, cb, cnt);
    k1zc_kernel<<<E_EDGES / BM, 256, 0, stream>>>(attr, ei, msk, Wb1, Zf, cnt);
    scan_kernel<<<1, 1024, 0, stream>>>(cnt, off, cur);
    fill_kernel<<<(E_EDGES + 255) / 256, 256, 0, stream>>>(ei, msk, cur, adj);
    gather_kernel<<<NN / 4, 256, 0, stream>>>(off, adj, Zf, hb);
    k2_kernel<<<E_EDGES / BM, 256, 0, stream>>>(attr, ei, msk, Bt2, cb, hb, out);
}